// Round 10
// baseline (39.814 us; speedup 1.0000x reference)
//
#include <hip/hip_runtime.h>

// QueryAndGroup: ball_query(r=0.2, nsample=32) + group xyz (centered) + group features.
// B=4, N=16384, M=2048, C=64. Output (B, 67, M, 32) f32.
//
// Ladder: R5 fused wave-per-query static = 36.8us (best); splits/queue/coop all
// regressed. This round keeps R5's structure, micro-fixes only:
//  - gather preloads all 8 float4 of the featT row before storing (miss overlap)
//  - nontemporal stores for out (70MB stream) and featT: stop thrashing L2,
//    keep xyz (scan working set) resident
//  - 128-thread blocks (2 waves): halves straggler coupling at block retirement,
//    still 32 waves/CU (16 wg/CU x 2)
//  - float4 transpose both sides (fewer issue slots, closer to BW floor)
// (R8 failed to compile: __builtin_nontemporal_store needs a clang ext_vector
//  type, not HIP_vector_type float4 -- fixed with vf4 alias.)

typedef float vf4 __attribute__((ext_vector_type(4)));

#define WPB 2
constexpr int Bc = 4, Nc = 16384, Mc = 2048, Cc = 64, Sc = 32;
constexpr int NQ = Bc * Mc;          // 8192 queries

__global__ __launch_bounds__(256) void transpose_kernel(
    const float* __restrict__ feat,  // (B, C, N)
    float* __restrict__ featT)       // (B, N, C)
{
    __shared__ float tile[64][65];
    const int b = blockIdx.y;
    const int nbase = blockIdx.x * 64;
    const int tid = threadIdx.x;
    const float* fb = feat + (size_t)b * Cc * Nc;
    float* ob = featT + (size_t)b * Nc * Cc;
    #pragma unroll
    for (int k = 0; k < 4; ++k) {                 // 16 channels / iter
        const int c  = (tid >> 4) + k * 16;
        const int n0 = (tid & 15) * 4;
        const vf4 v = *(const vf4*)&fb[(size_t)c * Nc + nbase + n0];  // 256B/16 lanes
        tile[n0][c] = v.x; tile[n0 + 1][c] = v.y;
        tile[n0 + 2][c] = v.z; tile[n0 + 3][c] = v.w;
    }
    __syncthreads();
    #pragma unroll
    for (int k = 0; k < 4; ++k) {                 // 16 rows / iter
        const int n  = (tid >> 4) + k * 16;
        const int c0 = (tid & 15) * 4;
        vf4 v;
        v.x = tile[n][c0];     v.y = tile[n][c0 + 1];
        v.z = tile[n][c0 + 2]; v.w = tile[n][c0 + 3];
        __builtin_nontemporal_store(v, (vf4*)&ob[(size_t)(nbase + n) * Cc + c0]);
    }
}

__global__ __launch_bounds__(128) void qg_kernel(
    const float* __restrict__ xyz,      // (B, N, 3)
    const float* __restrict__ new_xyz,  // (B, M, 3)
    const float* __restrict__ featT,    // (B, N, C)
    float* __restrict__ out)            // (B, 67, M, 32)
{
#pragma clang fp contract(off)
    const int lane = threadIdx.x & 63;
    const int wv   = threadIdx.x >> 6;
    const int q    = blockIdx.x * WPB + wv;
    const int b    = q >> 11;          // / Mc
    const int m    = q & (Mc - 1);

    __shared__ int sidx[WPB][Sc];

    const float r2 = 0.2f * 0.2f;
    const float* nz = new_xyz + (size_t)(b * Mc + m) * 3;
    const float qx = nz[0], qy = nz[1], qz = nz[2];
    const float* xb = xyz + (size_t)b * Nc * 3;

    int count = 0, firstIdx = 0;
    const unsigned long long lt = (1ull << lane) - 1ull;

    // Double-buffered scan: group k+1's 12 loads in flight while processing k.
    float px[4], py[4], pz[4];
    #pragma unroll
    for (int u = 0; u < 4; ++u) {
        const float* pp = xb + (size_t)(u * 64 + lane) * 3;
        px[u] = pp[0]; py[u] = pp[1]; pz[u] = pp[2];
    }
    for (int base = 0; base < Nc; base += 256) {
        const int nb = (base + 256 < Nc) ? base + 256 : base;   // clamped prefetch
        float nx[4], ny[4], nzv[4];
        #pragma unroll
        for (int u = 0; u < 4; ++u) {
            const float* pp = xb + (size_t)(nb + u * 64 + lane) * 3;
            nx[u] = pp[0]; ny[u] = pp[1]; nzv[u] = pp[2];
        }
        #pragma unroll
        for (int u = 0; u < 4; ++u) {
            const float dx = qx - px[u], dy = qy - py[u], dz = qz - pz[u];
            float d2 = dx * dx + dy * dy;   // no fma: match np/jax f32 rounding
            d2 = d2 + dz * dz;
            const bool in = d2 < r2;
            const unsigned long long mask = __ballot(in);
            if (in) {
                const int slot = count + __popcll(mask & lt);
                if (slot < Sc) sidx[wv][slot] = base + u * 64 + lane;
            }
            if (count == 0 && mask != 0ull)
                firstIdx = base + u * 64 + __builtin_ctzll(mask);
            count += __popcll(mask);
        }
        if (count >= Sc) break;             // wave-uniform
        #pragma unroll
        for (int u = 0; u < 4; ++u) { px[u] = nx[u]; py[u] = ny[u]; pz[u] = nzv[u]; }
    }
    {
        const int start = count < Sc ? count : Sc;
        if (start + lane < Sc) sidx[wv][start + lane] = firstIdx;
    }
    // Same-wave LDS visibility only; waves stay decoupled (no block barrier).
    asm volatile("s_waitcnt lgkmcnt(0)" ::: "memory");

    const int s     = lane & 31;
    const int chalf = lane >> 5;
    const int myid  = sidx[wv][s];
    float* ob = out + ((size_t)b * 67 * Mc + m) * Sc;

    // Preload the whole 256B featT row: 8 independent float4, misses overlap.
    const float* ftb = featT + ((size_t)b * Nc + myid) * Cc;
    vf4 vr[8];
    #pragma unroll
    for (int it = 0; it < 8; ++it)
        vr[it] = *(const vf4*)(ftb + (it * 2 + chalf) * 4);

    // Centered-xyz channels 0..2 (issued while featT misses are in flight).
    __builtin_nontemporal_store(
        xb[(size_t)myid * 3 + chalf] - (chalf ? qy : qx),
        &ob[(size_t)chalf * (Mc * Sc) + s]);
    if (chalf == 0)
        __builtin_nontemporal_store(
            xb[(size_t)myid * 3 + 2] - qz,
            &ob[(size_t)2 * (Mc * Sc) + s]);

    // Feature stores: 32 s-coalesced 128B-segment nt stores.
    #pragma unroll
    for (int it = 0; it < 8; ++it) {
        const int c4 = it * 2 + chalf;                  // 0..15
        #pragma unroll
        for (int k = 0; k < 4; ++k)
            __builtin_nontemporal_store(
                vr[it][k],
                &ob[(size_t)(3 + c4 * 4 + k) * (Mc * Sc) + s]);
    }
}

// Fallback if ws too small: fused kernel with direct (C,N) gather (same values).
__global__ __launch_bounds__(256) void qg_fallback_kernel(
    const float* __restrict__ xyz, const float* __restrict__ new_xyz,
    const float* __restrict__ feat, float* __restrict__ out)
{
#pragma clang fp contract(off)
    const int lane = threadIdx.x & 63;
    const int wv   = threadIdx.x >> 6;
    const int q    = blockIdx.x * 4 + wv;
    const int b    = q >> 11;
    const int m    = q & (Mc - 1);
    __shared__ int sidx[4][Sc];
    const float r2 = 0.2f * 0.2f;
    const float* nz = new_xyz + (size_t)(b * Mc + m) * 3;
    const float qx = nz[0], qy = nz[1], qz = nz[2];
    const float* xb = xyz + (size_t)b * Nc * 3;
    int count = 0, firstIdx = 0;
    const unsigned long long lt = (1ull << lane) - 1ull;
    for (int base = 0; base < Nc; base += 64) {
        const int i = base + lane;
        const float px = xb[i * 3], py = xb[i * 3 + 1], pz = xb[i * 3 + 2];
        const float dx = qx - px, dy = qy - py, dz = qz - pz;
        float d2 = dx * dx + dy * dy; d2 = d2 + dz * dz;
        const bool in = d2 < r2;
        const unsigned long long mask = __ballot(in);
        if (in) {
            const int slot = count + __popcll(mask & lt);
            if (slot < Sc) sidx[wv][slot] = i;
        }
        if (count == 0 && mask != 0ull) firstIdx = base + __builtin_ctzll(mask);
        count += __popcll(mask);
        if (count >= Sc) break;
    }
    const int start = count < Sc ? count : Sc;
    if (start + lane < Sc) sidx[wv][start + lane] = firstIdx;
    asm volatile("s_waitcnt lgkmcnt(0)" ::: "memory");
    const int s = lane & 31, chalf = lane >> 5;
    const int myid = sidx[wv][s];
    float* ob = out + ((size_t)b * 67 * Mc + m) * Sc;
    ob[(size_t)chalf * (Mc * Sc) + s] = xb[(size_t)myid * 3 + chalf] - (chalf ? qy : qx);
    if (chalf == 0)
        ob[(size_t)2 * (Mc * Sc) + s] = xb[(size_t)myid * 3 + 2] - qz;
    const float* fb = feat + (size_t)b * Cc * Nc;
    #pragma unroll
    for (int it = 0; it < 32; ++it) {
        const int c = it * 2 + chalf;
        ob[(size_t)(3 + c) * (Mc * Sc) + s] = fb[(size_t)c * Nc + myid];
    }
}

extern "C" void kernel_launch(void* const* d_in, const int* in_sizes, int n_in,
                              void* d_out, int out_size, void* d_ws, size_t ws_size,
                              hipStream_t stream) {
    const float* xyz     = (const float*)d_in[0];
    const float* new_xyz = (const float*)d_in[1];
    const float* feat    = (const float*)d_in[2];
    float* out           = (float*)d_out;

    const size_t featT_bytes = (size_t)Bc * Nc * Cc * sizeof(float);  // 16.8 MB

    if (ws_size >= featT_bytes) {
        float* featT = (float*)d_ws;
        hipLaunchKernelGGL(transpose_kernel, dim3(Nc / 64, Bc), dim3(256), 0, stream,
                           feat, featT);
        hipLaunchKernelGGL(qg_kernel, dim3(NQ / WPB), dim3(128), 0, stream,
                           xyz, new_xyz, featT, out);
    } else {
        hipLaunchKernelGGL(qg_fallback_kernel, dim3(NQ / 4), dim3(256), 0, stream,
                           xyz, new_xyz, feat, out);
    }
}

// Round 11
// 36.995 us; speedup vs baseline: 1.0762x; 1.0762x over previous
//
#include <hip/hip_runtime.h>

// QueryAndGroup: ball_query(r=0.2, nsample=32) + group xyz (centered) + group features.
// B=4, N=16384, M=2048, C=64. Output (B, 67, M, 32) f32.
//
// Ladder: R5 fused wave-per-query static = 36.8us best. R9's bundle (nt stores
// + WPB=2) regressed (nt featT stores bypass L2 -> gather re-reads from HBM).
// This round = exact R5 + ONE change: xyz packed to (N,4) float4 (xyz4 in ws,
// 1MB) so the scan loads 1 dwordx4/pt-chunk instead of 3 scalar dwords.
// Rationale: per-wave VMEM instrs were ~78 scan / ~42 gather+store; with 32
// waves/CU all L1-missing, TCP per-instruction throughput is the limiter.
// xyz4 cuts scan VMEM 3x (12 -> 4 per 256-pt group, fully coalesced 1KB each).

typedef float vf4 __attribute__((ext_vector_type(4)));

#define WPB 4
constexpr int Bc = 4, Nc = 16384, Mc = 2048, Cc = 64, Sc = 32;
constexpr int NQ = Bc * Mc;          // 8192 queries

// grid (Nc/64, Bc+1): y<Bc = transpose roles; y==Bc = xyz4 pack role.
__global__ __launch_bounds__(256) void prep_kernel(
    const float* __restrict__ feat,  // (B, C, N)
    const float* __restrict__ xyz,   // (B, N, 3)
    float* __restrict__ featT,       // (B, N, C)
    vf4* __restrict__ xyz4)          // (B*N) packed {x,y,z,0}
{
    if (blockIdx.y == Bc) {
        // pack role: 256 blocks x 256 thr = 65536 = Bc*Nc points, 1 pt/thread
        const int t = blockIdx.x * 256 + threadIdx.x;
        const float* p = xyz + (size_t)t * 3;
        vf4 v; v.x = p[0]; v.y = p[1]; v.z = p[2]; v.w = 0.0f;
        xyz4[t] = v;
        return;
    }
    __shared__ float tile[64][65];
    const int b = blockIdx.y;
    const int nbase = blockIdx.x * 64;
    const int tn = threadIdx.x & 63;
    const int tq = threadIdx.x >> 6;  // 0..3
    const float* fb = feat + (size_t)b * Cc * Nc;
    float* ob = featT + (size_t)b * Nc * Cc;
    #pragma unroll
    for (int k = 0; k < 16; ++k) {
        const int c = k * 4 + tq;
        tile[tn][c] = fb[(size_t)c * Nc + nbase + tn];      // coalesced reads
    }
    __syncthreads();
    #pragma unroll
    for (int k = 0; k < 16; ++k) {
        const int nl = k * 4 + tq;
        ob[(size_t)(nbase + nl) * Cc + tn] = tile[nl][tn];  // coalesced writes
    }
}

__global__ __launch_bounds__(256) void qg_kernel(
    const vf4* __restrict__ xyz4,       // (B*N) packed
    const float* __restrict__ new_xyz,  // (B, M, 3)
    const float* __restrict__ featT,    // (B, N, C)
    float* __restrict__ out)            // (B, 67, M, 32)
{
#pragma clang fp contract(off)
    const int lane = threadIdx.x & 63;
    const int wv   = threadIdx.x >> 6;
    const int q    = blockIdx.x * WPB + wv;
    const int b    = q >> 11;          // / Mc
    const int m    = q & (Mc - 1);

    __shared__ int sidx[WPB][Sc];

    const float r2 = 0.2f * 0.2f;
    const float* nz = new_xyz + (size_t)(b * Mc + m) * 3;
    const float qx = nz[0], qy = nz[1], qz = nz[2];
    const vf4* xb4 = xyz4 + (size_t)b * Nc;

    int count = 0, firstIdx = 0;
    const unsigned long long lt = (1ull << lane) - 1ull;

    // Double-buffered scan: group k+1's 4 dwordx4 loads in flight while
    // processing group k (each load: 64 lanes x 16B = 1KB coalesced).
    vf4 pv[4];
    #pragma unroll
    for (int u = 0; u < 4; ++u) pv[u] = xb4[u * 64 + lane];
    for (int base = 0; base < Nc; base += 256) {
        const int nb = (base + 256 < Nc) ? base + 256 : base;   // clamped prefetch
        vf4 nv[4];
        #pragma unroll
        for (int u = 0; u < 4; ++u) nv[u] = xb4[nb + u * 64 + lane];
        #pragma unroll
        for (int u = 0; u < 4; ++u) {
            const float dx = qx - pv[u].x, dy = qy - pv[u].y, dz = qz - pv[u].z;
            float d2 = dx * dx + dy * dy;   // no fma: match np/jax f32 rounding
            d2 = d2 + dz * dz;
            const bool in = d2 < r2;
            const unsigned long long mask = __ballot(in);
            if (in) {
                const int slot = count + __popcll(mask & lt);
                if (slot < Sc) sidx[wv][slot] = base + u * 64 + lane;
            }
            if (count == 0 && mask != 0ull)
                firstIdx = base + u * 64 + __builtin_ctzll(mask);
            count += __popcll(mask);
        }
        if (count >= Sc) break;             // wave-uniform
        #pragma unroll
        for (int u = 0; u < 4; ++u) pv[u] = nv[u];
    }
    {
        const int start = count < Sc ? count : Sc;
        if (start + lane < Sc) sidx[wv][start + lane] = firstIdx;
    }
    // Same-wave LDS visibility only; waves stay decoupled (no block barrier).
    asm volatile("s_waitcnt lgkmcnt(0)" ::: "memory");

    const int s     = lane & 31;
    const int chalf = lane >> 5;
    const int myid  = sidx[wv][s];
    float* ob = out + ((size_t)b * 67 * Mc + m) * Sc;

    // Centered-xyz channels 0..2: one dwordx4 per lane.
    {
        const vf4 p = xb4[myid];
        if (chalf == 0) {
            ob[(size_t)0 * (Mc * Sc) + s] = p.x - qx;
            ob[(size_t)2 * (Mc * Sc) + s] = p.z - qz;
        } else {
            ob[(size_t)1 * (Mc * Sc) + s] = p.y - qy;
        }
    }

    // Features: 256B-aligned featT row per sample, 8 float4 loads/lane,
    // stores as s-coalesced 128B segments (R5's interleave, unchanged).
    const float* ftb = featT + ((size_t)b * Nc + myid) * Cc;
    #pragma unroll
    for (int it = 0; it < 8; ++it) {
        const int c4 = it * 2 + chalf;                  // 0..15
        const vf4 v = *(const vf4*)(ftb + c4 * 4);
        #pragma unroll
        for (int k = 0; k < 4; ++k)
            ob[(size_t)(3 + c4 * 4 + k) * (Mc * Sc) + s] = v[k];
    }
}

// Fallback if ws too small: fused kernel with direct (C,N) gather (same values).
__global__ __launch_bounds__(256) void qg_fallback_kernel(
    const float* __restrict__ xyz, const float* __restrict__ new_xyz,
    const float* __restrict__ feat, float* __restrict__ out)
{
#pragma clang fp contract(off)
    const int lane = threadIdx.x & 63;
    const int wv   = threadIdx.x >> 6;
    const int q    = blockIdx.x * 4 + wv;
    const int b    = q >> 11;
    const int m    = q & (Mc - 1);
    __shared__ int sidx[4][Sc];
    const float r2 = 0.2f * 0.2f;
    const float* nz = new_xyz + (size_t)(b * Mc + m) * 3;
    const float qx = nz[0], qy = nz[1], qz = nz[2];
    const float* xb = xyz + (size_t)b * Nc * 3;
    int count = 0, firstIdx = 0;
    const unsigned long long lt = (1ull << lane) - 1ull;
    for (int base = 0; base < Nc; base += 64) {
        const int i = base + lane;
        const float px = xb[i * 3], py = xb[i * 3 + 1], pz = xb[i * 3 + 2];
        const float dx = qx - px, dy = qy - py, dz = qz - pz;
        float d2 = dx * dx + dy * dy; d2 = d2 + dz * dz;
        const bool in = d2 < r2;
        const unsigned long long mask = __ballot(in);
        if (in) {
            const int slot = count + __popcll(mask & lt);
            if (slot < Sc) sidx[wv][slot] = i;
        }
        if (count == 0 && mask != 0ull) firstIdx = base + __builtin_ctzll(mask);
        count += __popcll(mask);
        if (count >= Sc) break;
    }
    const int start = count < Sc ? count : Sc;
    if (start + lane < Sc) sidx[wv][start + lane] = firstIdx;
    asm volatile("s_waitcnt lgkmcnt(0)" ::: "memory");
    const int s = lane & 31, chalf = lane >> 5;
    const int myid = sidx[wv][s];
    float* ob = out + ((size_t)b * 67 * Mc + m) * Sc;
    ob[(size_t)chalf * (Mc * Sc) + s] = xb[(size_t)myid * 3 + chalf] - (chalf ? qy : qx);
    if (chalf == 0)
        ob[(size_t)2 * (Mc * Sc) + s] = xb[(size_t)myid * 3 + 2] - qz;
    const float* fb = feat + (size_t)b * Cc * Nc;
    #pragma unroll
    for (int it = 0; it < 32; ++it) {
        const int c = it * 2 + chalf;
        ob[(size_t)(3 + c) * (Mc * Sc) + s] = fb[(size_t)c * Nc + myid];
    }
}

extern "C" void kernel_launch(void* const* d_in, const int* in_sizes, int n_in,
                              void* d_out, int out_size, void* d_ws, size_t ws_size,
                              hipStream_t stream) {
    const float* xyz     = (const float*)d_in[0];
    const float* new_xyz = (const float*)d_in[1];
    const float* feat    = (const float*)d_in[2];
    float* out           = (float*)d_out;

    const size_t featT_bytes = (size_t)Bc * Nc * Cc * sizeof(float);  // 16.8 MB
    const size_t xyz4_bytes  = (size_t)Bc * Nc * sizeof(vf4);         //  1.0 MB

    if (ws_size >= featT_bytes + xyz4_bytes) {
        float* featT = (float*)d_ws;
        vf4*   xyz4  = (vf4*)((char*)d_ws + featT_bytes);
        hipLaunchKernelGGL(prep_kernel, dim3(Nc / 64, Bc + 1), dim3(256), 0, stream,
                           feat, xyz, featT, xyz4);
        hipLaunchKernelGGL(qg_kernel, dim3(NQ / WPB), dim3(256), 0, stream,
                           xyz4, new_xyz, featT, out);
    } else {
        hipLaunchKernelGGL(qg_fallback_kernel, dim3(NQ / 4), dim3(256), 0, stream,
                           xyz, new_xyz, feat, out);
    }
}

// Round 12
// 36.084 us; speedup vs baseline: 1.1034x; 1.0253x over previous
//
#include <hip/hip_runtime.h>

// QueryAndGroup: ball_query(r=0.2, nsample=32) + group xyz (centered) + group features.
// B=4, N=16384, M=2048, C=64. Output (B, 67, M, 32) f32.
//
// Ladder: R5/R11 fused wave-per-query = 36.8/37.0us. Diagnosis: gather reads
// 67MB of random 256B featT rows served from L3 (~450cy) with latency exposed
// per-iteration (loads interleaved with stores share vmcnt). This round:
//  1) preload all 8 float4 of the featT row (+xyz4 pt) BEFORE any store:
//     one latency exposure per query instead of eight (VGPR stays ~60: scan
//     double-buffer regs die before gather, R6 measured this pattern at 60).
//  2) XCD-batch swizzle: batch b's queries run on XCDs {2b,2b+1} (dispatch
//     round-robins blockIdx%8), so each batch's 4.2MB featT slice lives in
//     8MB of XCD-local L2 -> row reads become L2 hits instead of L3.

typedef float vf4 __attribute__((ext_vector_type(4)));

#define WPB 4
constexpr int Bc = 4, Nc = 16384, Mc = 2048, Cc = 64, Sc = 32;
constexpr int NQ = Bc * Mc;          // 8192 queries

// grid (Nc/64, Bc+1): y<Bc = transpose roles; y==Bc = xyz4 pack role.
__global__ __launch_bounds__(256) void prep_kernel(
    const float* __restrict__ feat,  // (B, C, N)
    const float* __restrict__ xyz,   // (B, N, 3)
    float* __restrict__ featT,       // (B, N, C)
    vf4* __restrict__ xyz4)          // (B*N) packed {x,y,z,0}
{
    if (blockIdx.y == Bc) {
        const int t = blockIdx.x * 256 + threadIdx.x;
        const float* p = xyz + (size_t)t * 3;
        vf4 v; v.x = p[0]; v.y = p[1]; v.z = p[2]; v.w = 0.0f;
        xyz4[t] = v;
        return;
    }
    __shared__ float tile[64][65];
    const int b = blockIdx.y;
    const int nbase = blockIdx.x * 64;
    const int tn = threadIdx.x & 63;
    const int tq = threadIdx.x >> 6;  // 0..3
    const float* fb = feat + (size_t)b * Cc * Nc;
    float* ob = featT + (size_t)b * Nc * Cc;
    #pragma unroll
    for (int k = 0; k < 16; ++k) {
        const int c = k * 4 + tq;
        tile[tn][c] = fb[(size_t)c * Nc + nbase + tn];      // coalesced reads
    }
    __syncthreads();
    #pragma unroll
    for (int k = 0; k < 16; ++k) {
        const int nl = k * 4 + tq;
        ob[(size_t)(nbase + nl) * Cc + tn] = tile[nl][tn];  // coalesced writes
    }
}

__global__ __launch_bounds__(256) void qg_kernel(
    const vf4* __restrict__ xyz4,       // (B*N) packed
    const float* __restrict__ new_xyz,  // (B, M, 3)
    const float* __restrict__ featT,    // (B, N, C)
    float* __restrict__ out)            // (B, 67, M, 32)
{
#pragma clang fp contract(off)
    const int lane = threadIdx.x & 63;
    const int wv   = threadIdx.x >> 6;

    // XCD-batch swizzle: xcd = blockIdx%8 (dispatch round-robin), batch = xcd/2,
    // m-chunk = (xcd&1)*1024 + (blockIdx/8)*4. 2048 blocks: 256 per XCD,
    // 512 per batch on its 2 XCDs.
    const int xcd = blockIdx.x & 7;
    const int b   = xcd >> 1;
    const int m   = ((xcd & 1) << 10) + (blockIdx.x >> 3) * WPB + wv;

    __shared__ int sidx[WPB][Sc];

    const float r2 = 0.2f * 0.2f;
    const float* nz = new_xyz + (size_t)(b * Mc + m) * 3;
    const float qx = nz[0], qy = nz[1], qz = nz[2];
    const vf4* xb4 = xyz4 + (size_t)b * Nc;

    int count = 0, firstIdx = 0;
    const unsigned long long lt = (1ull << lane) - 1ull;

    // Double-buffered scan (unchanged from R10/R11).
    vf4 pv[4];
    #pragma unroll
    for (int u = 0; u < 4; ++u) pv[u] = xb4[u * 64 + lane];
    for (int base = 0; base < Nc; base += 256) {
        const int nb = (base + 256 < Nc) ? base + 256 : base;   // clamped prefetch
        vf4 nv[4];
        #pragma unroll
        for (int u = 0; u < 4; ++u) nv[u] = xb4[nb + u * 64 + lane];
        #pragma unroll
        for (int u = 0; u < 4; ++u) {
            const float dx = qx - pv[u].x, dy = qy - pv[u].y, dz = qz - pv[u].z;
            float d2 = dx * dx + dy * dy;   // no fma: match np/jax f32 rounding
            d2 = d2 + dz * dz;
            const bool in = d2 < r2;
            const unsigned long long mask = __ballot(in);
            if (in) {
                const int slot = count + __popcll(mask & lt);
                if (slot < Sc) sidx[wv][slot] = base + u * 64 + lane;
            }
            if (count == 0 && mask != 0ull)
                firstIdx = base + u * 64 + __builtin_ctzll(mask);
            count += __popcll(mask);
        }
        if (count >= Sc) break;             // wave-uniform
        #pragma unroll
        for (int u = 0; u < 4; ++u) pv[u] = nv[u];
    }
    {
        const int start = count < Sc ? count : Sc;
        if (start + lane < Sc) sidx[wv][start + lane] = firstIdx;
    }
    // Same-wave LDS visibility only; waves stay decoupled (no block barrier).
    asm volatile("s_waitcnt lgkmcnt(0)" ::: "memory");

    const int s     = lane & 31;
    const int chalf = lane >> 5;
    const int myid  = sidx[wv][s];
    float* ob = out + ((size_t)b * 67 * Mc + m) * Sc;

    // ---- PRELOAD: all 9 loads issued before any store ----
    const float* ftb = featT + ((size_t)b * Nc + myid) * Cc;
    vf4 vr[8];
    #pragma unroll
    for (int it = 0; it < 8; ++it)
        vr[it] = *(const vf4*)(ftb + (it * 2 + chalf) * 4);
    const vf4 p = xb4[myid];

    // Centered-xyz channels 0..2.
    if (chalf == 0) {
        ob[(size_t)0 * (Mc * Sc) + s] = p.x - qx;
        ob[(size_t)2 * (Mc * Sc) + s] = p.z - qz;
    } else {
        ob[(size_t)1 * (Mc * Sc) + s] = p.y - qy;
    }

    // Feature stores: 32 s-coalesced 128B-segment stores.
    #pragma unroll
    for (int it = 0; it < 8; ++it) {
        const int c4 = it * 2 + chalf;                  // 0..15
        #pragma unroll
        for (int k = 0; k < 4; ++k)
            ob[(size_t)(3 + c4 * 4 + k) * (Mc * Sc) + s] = vr[it][k];
    }
}

// Fallback if ws too small: fused kernel with direct (C,N) gather (same values).
__global__ __launch_bounds__(256) void qg_fallback_kernel(
    const float* __restrict__ xyz, const float* __restrict__ new_xyz,
    const float* __restrict__ feat, float* __restrict__ out)
{
#pragma clang fp contract(off)
    const int lane = threadIdx.x & 63;
    const int wv   = threadIdx.x >> 6;
    const int q    = blockIdx.x * 4 + wv;
    const int b    = q >> 11;
    const int m    = q & (Mc - 1);
    __shared__ int sidx[4][Sc];
    const float r2 = 0.2f * 0.2f;
    const float* nz = new_xyz + (size_t)(b * Mc + m) * 3;
    const float qx = nz[0], qy = nz[1], qz = nz[2];
    const float* xb = xyz + (size_t)b * Nc * 3;
    int count = 0, firstIdx = 0;
    const unsigned long long lt = (1ull << lane) - 1ull;
    for (int base = 0; base < Nc; base += 64) {
        const int i = base + lane;
        const float px = xb[i * 3], py = xb[i * 3 + 1], pz = xb[i * 3 + 2];
        const float dx = qx - px, dy = qy - py, dz = qz - pz;
        float d2 = dx * dx + dy * dy; d2 = d2 + dz * dz;
        const bool in = d2 < r2;
        const unsigned long long mask = __ballot(in);
        if (in) {
            const int slot = count + __popcll(mask & lt);
            if (slot < Sc) sidx[wv][slot] = i;
        }
        if (count == 0 && mask != 0ull) firstIdx = base + __builtin_ctzll(mask);
        count += __popcll(mask);
        if (count >= Sc) break;
    }
    const int start = count < Sc ? count : Sc;
    if (start + lane < Sc) sidx[wv][start + lane] = firstIdx;
    asm volatile("s_waitcnt lgkmcnt(0)" ::: "memory");
    const int s = lane & 31, chalf = lane >> 5;
    const int myid = sidx[wv][s];
    float* ob = out + ((size_t)b * 67 * Mc + m) * Sc;
    ob[(size_t)chalf * (Mc * Sc) + s] = xb[(size_t)myid * 3 + chalf] - (chalf ? qy : qx);
    if (chalf == 0)
        ob[(size_t)2 * (Mc * Sc) + s] = xb[(size_t)myid * 3 + 2] - qz;
    const float* fb = feat + (size_t)b * Cc * Nc;
    #pragma unroll
    for (int it = 0; it < 32; ++it) {
        const int c = it * 2 + chalf;
        ob[(size_t)(3 + c) * (Mc * Sc) + s] = fb[(size_t)c * Nc + myid];
    }
}

extern "C" void kernel_launch(void* const* d_in, const int* in_sizes, int n_in,
                              void* d_out, int out_size, void* d_ws, size_t ws_size,
                              hipStream_t stream) {
    const float* xyz     = (const float*)d_in[0];
    const float* new_xyz = (const float*)d_in[1];
    const float* feat    = (const float*)d_in[2];
    float* out           = (float*)d_out;

    const size_t featT_bytes = (size_t)Bc * Nc * Cc * sizeof(float);  // 16.8 MB
    const size_t xyz4_bytes  = (size_t)Bc * Nc * sizeof(vf4);         //  1.0 MB

    if (ws_size >= featT_bytes + xyz4_bytes) {
        float* featT = (float*)d_ws;
        vf4*   xyz4  = (vf4*)((char*)d_ws + featT_bytes);
        hipLaunchKernelGGL(prep_kernel, dim3(Nc / 64, Bc + 1), dim3(256), 0, stream,
                           feat, xyz, featT, xyz4);
        hipLaunchKernelGGL(qg_kernel, dim3(NQ / WPB), dim3(256), 0, stream,
                           xyz4, new_xyz, featT, out);
    } else {
        hipLaunchKernelGGL(qg_fallback_kernel, dim3(NQ / 4), dim3(256), 0, stream,
                           xyz, new_xyz, feat, out);
    }
}

// Round 13
// 35.095 us; speedup vs baseline: 1.1345x; 1.0282x over previous
//
#include <hip/hip_runtime.h>

// QueryAndGroup: ball_query(r=0.2, nsample=32) + group xyz (centered) + group features.
// B=4, N=16384, M=2048, C=64. Output (B, 67, M, 32) f32.
//
// Ladder: R5 36.8 -> R11 36.1us (preload + XCD-batch swizzle). This round is a
// single-variable experiment on the store path: R11 EXACTLY, plus nontemporal
// (no-allocate) stores on the OUTPUT only. Theory: 68.6MB of streaming output
// write-allocates in L2, displacing featT/xyz4 read working set and
// fragmenting HBM write-back; nt stores should stop the displacement.
// (R9 bundled nt on featT too -- which the gather re-reads -- so its regression
// doesn't falsify this.) featT/xyz4 loads and prep kernel unchanged.

typedef float vf4 __attribute__((ext_vector_type(4)));

#define WPB 4
constexpr int Bc = 4, Nc = 16384, Mc = 2048, Cc = 64, Sc = 32;
constexpr int NQ = Bc * Mc;          // 8192 queries

// grid (Nc/64, Bc+1): y<Bc = transpose roles; y==Bc = xyz4 pack role.
__global__ __launch_bounds__(256) void prep_kernel(
    const float* __restrict__ feat,  // (B, C, N)
    const float* __restrict__ xyz,   // (B, N, 3)
    float* __restrict__ featT,       // (B, N, C)
    vf4* __restrict__ xyz4)          // (B*N) packed {x,y,z,0}
{
    if (blockIdx.y == Bc) {
        const int t = blockIdx.x * 256 + threadIdx.x;
        const float* p = xyz + (size_t)t * 3;
        vf4 v; v.x = p[0]; v.y = p[1]; v.z = p[2]; v.w = 0.0f;
        xyz4[t] = v;
        return;
    }
    __shared__ float tile[64][65];
    const int b = blockIdx.y;
    const int nbase = blockIdx.x * 64;
    const int tn = threadIdx.x & 63;
    const int tq = threadIdx.x >> 6;  // 0..3
    const float* fb = feat + (size_t)b * Cc * Nc;
    float* ob = featT + (size_t)b * Nc * Cc;
    #pragma unroll
    for (int k = 0; k < 16; ++k) {
        const int c = k * 4 + tq;
        tile[tn][c] = fb[(size_t)c * Nc + nbase + tn];      // coalesced reads
    }
    __syncthreads();
    #pragma unroll
    for (int k = 0; k < 16; ++k) {
        const int nl = k * 4 + tq;
        ob[(size_t)(nbase + nl) * Cc + tn] = tile[nl][tn];  // coalesced writes
    }
}

__global__ __launch_bounds__(256) void qg_kernel(
    const vf4* __restrict__ xyz4,       // (B*N) packed
    const float* __restrict__ new_xyz,  // (B, M, 3)
    const float* __restrict__ featT,    // (B, N, C)
    float* __restrict__ out)            // (B, 67, M, 32)
{
#pragma clang fp contract(off)
    const int lane = threadIdx.x & 63;
    const int wv   = threadIdx.x >> 6;

    // XCD-batch swizzle: xcd = blockIdx%8 (dispatch round-robin), batch = xcd/2,
    // m-chunk = (xcd&1)*1024 + (blockIdx/8)*4.
    const int xcd = blockIdx.x & 7;
    const int b   = xcd >> 1;
    const int m   = ((xcd & 1) << 10) + (blockIdx.x >> 3) * WPB + wv;

    __shared__ int sidx[WPB][Sc];

    const float r2 = 0.2f * 0.2f;
    const float* nz = new_xyz + (size_t)(b * Mc + m) * 3;
    const float qx = nz[0], qy = nz[1], qz = nz[2];
    const vf4* xb4 = xyz4 + (size_t)b * Nc;

    int count = 0, firstIdx = 0;
    const unsigned long long lt = (1ull << lane) - 1ull;

    // Double-buffered scan (unchanged).
    vf4 pv[4];
    #pragma unroll
    for (int u = 0; u < 4; ++u) pv[u] = xb4[u * 64 + lane];
    for (int base = 0; base < Nc; base += 256) {
        const int nb = (base + 256 < Nc) ? base + 256 : base;   // clamped prefetch
        vf4 nv[4];
        #pragma unroll
        for (int u = 0; u < 4; ++u) nv[u] = xb4[nb + u * 64 + lane];
        #pragma unroll
        for (int u = 0; u < 4; ++u) {
            const float dx = qx - pv[u].x, dy = qy - pv[u].y, dz = qz - pv[u].z;
            float d2 = dx * dx + dy * dy;   // no fma: match np/jax f32 rounding
            d2 = d2 + dz * dz;
            const bool in = d2 < r2;
            const unsigned long long mask = __ballot(in);
            if (in) {
                const int slot = count + __popcll(mask & lt);
                if (slot < Sc) sidx[wv][slot] = base + u * 64 + lane;
            }
            if (count == 0 && mask != 0ull)
                firstIdx = base + u * 64 + __builtin_ctzll(mask);
            count += __popcll(mask);
        }
        if (count >= Sc) break;             // wave-uniform
        #pragma unroll
        for (int u = 0; u < 4; ++u) pv[u] = nv[u];
    }
    {
        const int start = count < Sc ? count : Sc;
        if (start + lane < Sc) sidx[wv][start + lane] = firstIdx;
    }
    // Same-wave LDS visibility only; waves stay decoupled (no block barrier).
    asm volatile("s_waitcnt lgkmcnt(0)" ::: "memory");

    const int s     = lane & 31;
    const int chalf = lane >> 5;
    const int myid  = sidx[wv][s];
    float* ob = out + ((size_t)b * 67 * Mc + m) * Sc;

    // ---- PRELOAD: all 9 loads issued before any store ----
    const float* ftb = featT + ((size_t)b * Nc + myid) * Cc;
    vf4 vr[8];
    #pragma unroll
    for (int it = 0; it < 8; ++it)
        vr[it] = *(const vf4*)(ftb + (it * 2 + chalf) * 4);
    const vf4 p = xb4[myid];

    // Centered-xyz channels 0..2 (nt stores: no L2 allocate on the out stream).
    if (chalf == 0) {
        __builtin_nontemporal_store(p.x - qx, &ob[(size_t)0 * (Mc * Sc) + s]);
        __builtin_nontemporal_store(p.z - qz, &ob[(size_t)2 * (Mc * Sc) + s]);
    } else {
        __builtin_nontemporal_store(p.y - qy, &ob[(size_t)1 * (Mc * Sc) + s]);
    }

    // Feature stores: 32 s-coalesced 128B-segment nt stores.
    #pragma unroll
    for (int it = 0; it < 8; ++it) {
        const int c4 = it * 2 + chalf;                  // 0..15
        #pragma unroll
        for (int k = 0; k < 4; ++k)
            __builtin_nontemporal_store(
                vr[it][k], &ob[(size_t)(3 + c4 * 4 + k) * (Mc * Sc) + s]);
    }
}

// Fallback if ws too small: fused kernel with direct (C,N) gather (same values).
__global__ __launch_bounds__(256) void qg_fallback_kernel(
    const float* __restrict__ xyz, const float* __restrict__ new_xyz,
    const float* __restrict__ feat, float* __restrict__ out)
{
#pragma clang fp contract(off)
    const int lane = threadIdx.x & 63;
    const int wv   = threadIdx.x >> 6;
    const int q    = blockIdx.x * 4 + wv;
    const int b    = q >> 11;
    const int m    = q & (Mc - 1);
    __shared__ int sidx[4][Sc];
    const float r2 = 0.2f * 0.2f;
    const float* nz = new_xyz + (size_t)(b * Mc + m) * 3;
    const float qx = nz[0], qy = nz[1], qz = nz[2];
    const float* xb = xyz + (size_t)b * Nc * 3;
    int count = 0, firstIdx = 0;
    const unsigned long long lt = (1ull << lane) - 1ull;
    for (int base = 0; base < Nc; base += 64) {
        const int i = base + lane;
        const float px = xb[i * 3], py = xb[i * 3 + 1], pz = xb[i * 3 + 2];
        const float dx = qx - px, dy = qy - py, dz = qz - pz;
        float d2 = dx * dx + dy * dy; d2 = d2 + dz * dz;
        const bool in = d2 < r2;
        const unsigned long long mask = __ballot(in);
        if (in) {
            const int slot = count + __popcll(mask & lt);
            if (slot < Sc) sidx[wv][slot] = i;
        }
        if (count == 0 && mask != 0ull) firstIdx = base + __builtin_ctzll(mask);
        count += __popcll(mask);
        if (count >= Sc) break;
    }
    const int start = count < Sc ? count : Sc;
    if (start + lane < Sc) sidx[wv][start + lane] = firstIdx;
    asm volatile("s_waitcnt lgkmcnt(0)" ::: "memory");
    const int s = lane & 31, chalf = lane >> 5;
    const int myid = sidx[wv][s];
    float* ob = out + ((size_t)b * 67 * Mc + m) * Sc;
    ob[(size_t)chalf * (Mc * Sc) + s] = xb[(size_t)myid * 3 + chalf] - (chalf ? qy : qx);
    if (chalf == 0)
        ob[(size_t)2 * (Mc * Sc) + s] = xb[(size_t)myid * 3 + 2] - qz;
    const float* fb = feat + (size_t)b * Cc * Nc;
    #pragma unroll
    for (int it = 0; it < 32; ++it) {
        const int c = it * 2 + chalf;
        ob[(size_t)(3 + c) * (Mc * Sc) + s] = fb[(size_t)c * Nc + myid];
    }
}

extern "C" void kernel_launch(void* const* d_in, const int* in_sizes, int n_in,
                              void* d_out, int out_size, void* d_ws, size_t ws_size,
                              hipStream_t stream) {
    const float* xyz     = (const float*)d_in[0];
    const float* new_xyz = (const float*)d_in[1];
    const float* feat    = (const float*)d_in[2];
    float* out           = (float*)d_out;

    const size_t featT_bytes = (size_t)Bc * Nc * Cc * sizeof(float);  // 16.8 MB
    const size_t xyz4_bytes  = (size_t)Bc * Nc * sizeof(vf4);         //  1.0 MB

    if (ws_size >= featT_bytes + xyz4_bytes) {
        float* featT = (float*)d_ws;
        vf4*   xyz4  = (vf4*)((char*)d_ws + featT_bytes);
        hipLaunchKernelGGL(prep_kernel, dim3(Nc / 64, Bc + 1), dim3(256), 0, stream,
                           feat, xyz, featT, xyz4);
        hipLaunchKernelGGL(qg_kernel, dim3(NQ / WPB), dim3(256), 0, stream,
                           xyz4, new_xyz, featT, out);
    } else {
        hipLaunchKernelGGL(qg_fallback_kernel, dim3(NQ / 4), dim3(256), 0, stream,
                           xyz, new_xyz, feat, out);
    }
}

// Round 14
// 34.660 us; speedup vs baseline: 1.1487x; 1.0126x over previous
//
#include <hip/hip_runtime.h>

// QueryAndGroup: ball_query(r=0.2, nsample=32) + group xyz (centered) + group features.
// B=4, N=16384, M=2048, C=64. Output (B, 67, M, 32) f32.
//
// Ladder: R5 36.8 -> R11 36.1 (preload + XCD swizzle) -> R12 35.1 (nt output
// stores). This round, single variable: WPB 4 -> 2 (128-thread blocks).
// Theory: residual is intra-block straggler coupling -- block retires on its
// slowest wave (corner queries scan ~8x mean); max-of-2 < max-of-4, and the CU
// backfills retired blocks (16 wg/CU x 2 waves = full 32 waves/CU).
// Everything else identical to R12.

typedef float vf4 __attribute__((ext_vector_type(4)));

#define WPB 2
constexpr int Bc = 4, Nc = 16384, Mc = 2048, Cc = 64, Sc = 32;
constexpr int NQ = Bc * Mc;          // 8192 queries

// grid (Nc/64, Bc+1): y<Bc = transpose roles; y==Bc = xyz4 pack role.
__global__ __launch_bounds__(256) void prep_kernel(
    const float* __restrict__ feat,  // (B, C, N)
    const float* __restrict__ xyz,   // (B, N, 3)
    float* __restrict__ featT,       // (B, N, C)
    vf4* __restrict__ xyz4)          // (B*N) packed {x,y,z,0}
{
    if (blockIdx.y == Bc) {
        const int t = blockIdx.x * 256 + threadIdx.x;
        const float* p = xyz + (size_t)t * 3;
        vf4 v; v.x = p[0]; v.y = p[1]; v.z = p[2]; v.w = 0.0f;
        xyz4[t] = v;
        return;
    }
    __shared__ float tile[64][65];
    const int b = blockIdx.y;
    const int nbase = blockIdx.x * 64;
    const int tn = threadIdx.x & 63;
    const int tq = threadIdx.x >> 6;  // 0..3
    const float* fb = feat + (size_t)b * Cc * Nc;
    float* ob = featT + (size_t)b * Nc * Cc;
    #pragma unroll
    for (int k = 0; k < 16; ++k) {
        const int c = k * 4 + tq;
        tile[tn][c] = fb[(size_t)c * Nc + nbase + tn];      // coalesced reads
    }
    __syncthreads();
    #pragma unroll
    for (int k = 0; k < 16; ++k) {
        const int nl = k * 4 + tq;
        ob[(size_t)(nbase + nl) * Cc + tn] = tile[nl][tn];  // coalesced writes
    }
}

__global__ __launch_bounds__(128) void qg_kernel(
    const vf4* __restrict__ xyz4,       // (B*N) packed
    const float* __restrict__ new_xyz,  // (B, M, 3)
    const float* __restrict__ featT,    // (B, N, C)
    float* __restrict__ out)            // (B, 67, M, 32)
{
#pragma clang fp contract(off)
    const int lane = threadIdx.x & 63;
    const int wv   = threadIdx.x >> 6;

    // XCD-batch swizzle: xcd = blockIdx%8 (dispatch round-robin), batch = xcd/2,
    // m-chunk = (xcd&1)*1024 + (blockIdx/8)*2. 4096 blocks: 512/XCD, 1024/batch.
    const int xcd = blockIdx.x & 7;
    const int b   = xcd >> 1;
    const int m   = ((xcd & 1) << 10) + (blockIdx.x >> 3) * WPB + wv;

    __shared__ int sidx[WPB][Sc];

    const float r2 = 0.2f * 0.2f;
    const float* nz = new_xyz + (size_t)(b * Mc + m) * 3;
    const float qx = nz[0], qy = nz[1], qz = nz[2];
    const vf4* xb4 = xyz4 + (size_t)b * Nc;

    int count = 0, firstIdx = 0;
    const unsigned long long lt = (1ull << lane) - 1ull;

    // Double-buffered scan (unchanged).
    vf4 pv[4];
    #pragma unroll
    for (int u = 0; u < 4; ++u) pv[u] = xb4[u * 64 + lane];
    for (int base = 0; base < Nc; base += 256) {
        const int nb = (base + 256 < Nc) ? base + 256 : base;   // clamped prefetch
        vf4 nv[4];
        #pragma unroll
        for (int u = 0; u < 4; ++u) nv[u] = xb4[nb + u * 64 + lane];
        #pragma unroll
        for (int u = 0; u < 4; ++u) {
            const float dx = qx - pv[u].x, dy = qy - pv[u].y, dz = qz - pv[u].z;
            float d2 = dx * dx + dy * dy;   // no fma: match np/jax f32 rounding
            d2 = d2 + dz * dz;
            const bool in = d2 < r2;
            const unsigned long long mask = __ballot(in);
            if (in) {
                const int slot = count + __popcll(mask & lt);
                if (slot < Sc) sidx[wv][slot] = base + u * 64 + lane;
            }
            if (count == 0 && mask != 0ull)
                firstIdx = base + u * 64 + __builtin_ctzll(mask);
            count += __popcll(mask);
        }
        if (count >= Sc) break;             // wave-uniform
        #pragma unroll
        for (int u = 0; u < 4; ++u) pv[u] = nv[u];
    }
    {
        const int start = count < Sc ? count : Sc;
        if (start + lane < Sc) sidx[wv][start + lane] = firstIdx;
    }
    // Same-wave LDS visibility only; waves stay decoupled (no block barrier).
    asm volatile("s_waitcnt lgkmcnt(0)" ::: "memory");

    const int s     = lane & 31;
    const int chalf = lane >> 5;
    const int myid  = sidx[wv][s];
    float* ob = out + ((size_t)b * 67 * Mc + m) * Sc;

    // ---- PRELOAD: all 9 loads issued before any store ----
    const float* ftb = featT + ((size_t)b * Nc + myid) * Cc;
    vf4 vr[8];
    #pragma unroll
    for (int it = 0; it < 8; ++it)
        vr[it] = *(const vf4*)(ftb + (it * 2 + chalf) * 4);
    const vf4 p = xb4[myid];

    // Centered-xyz channels 0..2 (nt stores: no L2 allocate on the out stream).
    if (chalf == 0) {
        __builtin_nontemporal_store(p.x - qx, &ob[(size_t)0 * (Mc * Sc) + s]);
        __builtin_nontemporal_store(p.z - qz, &ob[(size_t)2 * (Mc * Sc) + s]);
    } else {
        __builtin_nontemporal_store(p.y - qy, &ob[(size_t)1 * (Mc * Sc) + s]);
    }

    // Feature stores: 32 s-coalesced 128B-segment nt stores.
    #pragma unroll
    for (int it = 0; it < 8; ++it) {
        const int c4 = it * 2 + chalf;                  // 0..15
        #pragma unroll
        for (int k = 0; k < 4; ++k)
            __builtin_nontemporal_store(
                vr[it][k], &ob[(size_t)(3 + c4 * 4 + k) * (Mc * Sc) + s]);
    }
}

// Fallback if ws too small: fused kernel with direct (C,N) gather (same values).
__global__ __launch_bounds__(256) void qg_fallback_kernel(
    const float* __restrict__ xyz, const float* __restrict__ new_xyz,
    const float* __restrict__ feat, float* __restrict__ out)
{
#pragma clang fp contract(off)
    const int lane = threadIdx.x & 63;
    const int wv   = threadIdx.x >> 6;
    const int q    = blockIdx.x * 4 + wv;
    const int b    = q >> 11;
    const int m    = q & (Mc - 1);
    __shared__ int sidx[4][Sc];
    const float r2 = 0.2f * 0.2f;
    const float* nz = new_xyz + (size_t)(b * Mc + m) * 3;
    const float qx = nz[0], qy = nz[1], qz = nz[2];
    const float* xb = xyz + (size_t)b * Nc * 3;
    int count = 0, firstIdx = 0;
    const unsigned long long lt = (1ull << lane) - 1ull;
    for (int base = 0; base < Nc; base += 64) {
        const int i = base + lane;
        const float px = xb[i * 3], py = xb[i * 3 + 1], pz = xb[i * 3 + 2];
        const float dx = qx - px, dy = qy - py, dz = qz - pz;
        float d2 = dx * dx + dy * dy; d2 = d2 + dz * dz;
        const bool in = d2 < r2;
        const unsigned long long mask = __ballot(in);
        if (in) {
            const int slot = count + __popcll(mask & lt);
            if (slot < Sc) sidx[wv][slot] = i;
        }
        if (count == 0 && mask != 0ull) firstIdx = base + __builtin_ctzll(mask);
        count += __popcll(mask);
        if (count >= Sc) break;
    }
    const int start = count < Sc ? count : Sc;
    if (start + lane < Sc) sidx[wv][start + lane] = firstIdx;
    asm volatile("s_waitcnt lgkmcnt(0)" ::: "memory");
    const int s = lane & 31, chalf = lane >> 5;
    const int myid = sidx[wv][s];
    float* ob = out + ((size_t)b * 67 * Mc + m) * Sc;
    ob[(size_t)chalf * (Mc * Sc) + s] = xb[(size_t)myid * 3 + chalf] - (chalf ? qy : qx);
    if (chalf == 0)
        ob[(size_t)2 * (Mc * Sc) + s] = xb[(size_t)myid * 3 + 2] - qz;
    const float* fb = feat + (size_t)b * Cc * Nc;
    #pragma unroll
    for (int it = 0; it < 32; ++it) {
        const int c = it * 2 + chalf;
        ob[(size_t)(3 + c) * (Mc * Sc) + s] = fb[(size_t)c * Nc + myid];
    }
}

extern "C" void kernel_launch(void* const* d_in, const int* in_sizes, int n_in,
                              void* d_out, int out_size, void* d_ws, size_t ws_size,
                              hipStream_t stream) {
    const float* xyz     = (const float*)d_in[0];
    const float* new_xyz = (const float*)d_in[1];
    const float* feat    = (const float*)d_in[2];
    float* out           = (float*)d_out;

    const size_t featT_bytes = (size_t)Bc * Nc * Cc * sizeof(float);  // 16.8 MB
    const size_t xyz4_bytes  = (size_t)Bc * Nc * sizeof(vf4);         //  1.0 MB

    if (ws_size >= featT_bytes + xyz4_bytes) {
        float* featT = (float*)d_ws;
        vf4*   xyz4  = (vf4*)((char*)d_ws + featT_bytes);
        hipLaunchKernelGGL(prep_kernel, dim3(Nc / 64, Bc + 1), dim3(256), 0, stream,
                           feat, xyz, featT, xyz4);
        hipLaunchKernelGGL(qg_kernel, dim3(NQ / WPB), dim3(128), 0, stream,
                           xyz4, new_xyz, featT, out);
    } else {
        hipLaunchKernelGGL(qg_fallback_kernel, dim3(NQ / 4), dim3(256), 0, stream,
                           xyz, new_xyz, feat, out);
    }
}